// Round 4
// baseline (100.021 us; speedup 1.0000x reference)
//
#include <hip/hip_runtime.h>
#include <hip/hip_bf16.h>

typedef unsigned int uint;
typedef unsigned short ushort;

// Dims
#define Bn 16
#define Dd 256
#define Nn 4096
#define Hh 4
#define Kk 16
#define Vv 64
#define Rr 23
#define Cc 144   // 64 q + 16 k + 64 v

typedef short bf16x8s __attribute__((ext_vector_type(8)));
typedef float f32x4 __attribute__((ext_vector_type(4)));

static __device__ __forceinline__ ushort f2bf(float f) {
    __hip_bfloat16 h = __float2bfloat16(f);
    return __builtin_bit_cast(ushort, h);
}
static __device__ __forceinline__ float bf2f(ushort u) {
    return __uint_as_float(((uint)u) << 16);
}

// ---------------- Kernel 1: pack BN-folded weights (bf16, A-fragment order) ----------------
__global__ __launch_bounds__(256) void pack_kernel(
    const float* __restrict__ Wq, const float* __restrict__ qg, const float* __restrict__ qb,
    const float* __restrict__ qm, const float* __restrict__ qv,
    const float* __restrict__ Wk, const float* __restrict__ Wv,
    const float* __restrict__ vg, const float* __restrict__ vb,
    const float* __restrict__ vm, const float* __restrict__ vvar,
    ushort* __restrict__ Wf16, float* __restrict__ bias) {
    int c = blockIdx.x;       // 0..143
    int d = threadIdx.x;      // 0..255
    float scale, bs;
    const float* src;
    if (c < 64) {
        scale = qg[c] * rsqrtf(qv[c] + 1e-5f);
        bs = qb[c] - qm[c] * scale;
        src = Wq + c * Dd;
    } else if (c < 80) {
        scale = 1.f; bs = 0.f;
        src = Wk + (c - 64) * Dd;
    } else {
        int j = c - 80;
        scale = vg[j] * rsqrtf(vvar[j] + 1e-5f);
        bs = vb[j] - vm[j] * scale;
        src = Wv + j * Dd;
    }
    int rt = c >> 4, lm = c & 15;
    int kk = d >> 5, hi = (d >> 3) & 3, j = d & 7;
    int idx = ((rt * 8 + kk) * 64 + hi * 16 + lm) * 8 + j;
    Wf16[idx] = f2bf(src[d] * scale);
    if (d == 0) bias[c] = bs;
}

// ---------------- Kernel 2: MFMA projection y[b][144][4096] ----------------
__global__ __launch_bounds__(256, 4) void proj_mfma_kernel(
    const float* __restrict__ x, const ushort* __restrict__ Wf16,
    const float* __restrict__ bias, float* __restrict__ y) {
    __shared__ ushort Wlds[9 * 4 * 64 * 8];   // 36864 B

    int b = blockIdx.y;
    int n0 = blockIdx.x * 64;
    int t = threadIdx.x;
    int w = t >> 6;            // wave 0..3
    int l = t & 63;
    int lm = l & 15;
    int hi = l >> 4;           // 0..3
    int n = n0 + w * 16 + lm;  // this lane's output column

    const uint* WfU = (const uint*)Wf16;
    uint* WldsU = (uint*)Wlds;

    f32x4 acc[9];
#pragma unroll
    for (int rt = 0; rt < 9; rt++) acc[rt] = (f32x4){0.f, 0.f, 0.f, 0.f};

    const float* xb = x + (size_t)b * Dd * Nn + n;

#pragma unroll
    for (int p = 0; p < 2; p++) {
        int kb = p * 4;
        if (p) __syncthreads();
#pragma unroll
        for (int i = 0; i < 36; i++) {
            int flat = t + 256 * i;
            int f2 = flat >> 8;        // rt*4 + kkl
            int within = flat & 255;
            int rt = f2 >> 2, kkl = f2 & 3;
            WldsU[flat] = WfU[((rt * 8 + kb + kkl) << 8) + within];
        }
        __syncthreads();

#pragma unroll
        for (int kkl = 0; kkl < 4; kkl++) {
            int kk = kb + kkl;
            const float* xp = xb + (size_t)(kk * 32 + hi * 8) * Nn;
            float f[8];
#pragma unroll
            for (int j = 0; j < 8; j++) f[j] = xp[(size_t)j * Nn];
            bf16x8s bfrag;
#pragma unroll
            for (int j = 0; j < 8; j++) bfrag[j] = (short)f2bf(f[j]);
#pragma unroll
            for (int rt = 0; rt < 9; rt++) {
                bf16x8s afrag = *reinterpret_cast<const bf16x8s*>(
                    &Wlds[(size_t)((rt * 4 + kkl) * 64 + l) * 8]);
                acc[rt] = __builtin_amdgcn_mfma_f32_16x16x32_bf16(afrag, bfrag, acc[rt], 0, 0, 0);
            }
        }
    }

    float* yb = y + (size_t)b * Cc * Nn + n;
#pragma unroll
    for (int rt = 0; rt < 9; rt++) {
#pragma unroll
        for (int r = 0; r < 4; r++) {
            int c = rt * 16 + hi * 4 + r;
            yb[(size_t)c * Nn] = acc[rt][r] + bias[c];
        }
    }
}

// ---------------- Kernel 3: softmax over n for k channels ----------------
__global__ __launch_bounds__(256) void softmax_kernel(float* __restrict__ y) {
    int b = blockIdx.y, kc = blockIdx.x;
    float* row = y + ((size_t)b * Cc + 64 + kc) * Nn;
    int t = threadIdx.x;
    float vals[16];
    float m = -1e30f;
#pragma unroll
    for (int i = 0; i < 16; i++) {
        vals[i] = row[t + 256 * i];
        m = fmaxf(m, vals[i]);
    }
#pragma unroll
    for (int off = 32; off; off >>= 1) m = fmaxf(m, __shfl_xor(m, off));
    __shared__ float sm[4], ss[4];
    int wave = t >> 6;
    if ((t & 63) == 0) sm[wave] = m;
    __syncthreads();
    m = fmaxf(fmaxf(sm[0], sm[1]), fmaxf(sm[2], sm[3]));
    float s = 0.f;
#pragma unroll
    for (int i = 0; i < 16; i++) {
        vals[i] = __expf(vals[i] - m);
        s += vals[i];
    }
#pragma unroll
    for (int off = 32; off; off >>= 1) s += __shfl_xor(s, off);
    if ((t & 63) == 0) ss[wave] = s;
    __syncthreads();
    s = ss[0] + ss[1] + ss[2] + ss[3];
    float inv = 1.f / s;
#pragma unroll
    for (int i = 0; i < 16; i++) row[t + 256 * i] = vals[i] * inv;
}

// ---------------- Kernel 4: lam_c[b][16][64] = sum_n kk*vv ----------------
#define NCHUNK 128
__global__ __launch_bounds__(256) void lamc_kernel(
    const float* __restrict__ y, float* __restrict__ lam) {
    int b = blockIdx.y, ch = blockIdx.x;
    int n0 = ch * NCHUNK;
    __shared__ float kks[Kk][NCHUNK + 1];
    __shared__ float vvs[Vv][NCHUNK + 1];
    const float* yb = y + (size_t)b * Cc * Nn;
    int t = threadIdx.x;
#pragma unroll
    for (int i = 0; i < (Kk * NCHUNK) / 256; i++) {
        int idx = t + 256 * i;
        int r = idx >> 7, n = idx & 127;
        kks[r][n] = yb[(size_t)(64 + r) * Nn + n0 + n];
    }
#pragma unroll
    for (int i = 0; i < (Vv * NCHUNK) / 256; i++) {
        int idx = t + 256 * i;
        int r = idx >> 7, n = idx & 127;
        vvs[r][n] = yb[(size_t)(80 + r) * Nn + n0 + n];
    }
    __syncthreads();
    int v = t & 63;
    int k0 = t >> 6;   // 0..3
    float acc[4] = {0.f, 0.f, 0.f, 0.f};
    for (int n = 0; n < NCHUNK; n++) {
        float wv = vvs[v][n];
#pragma unroll
        for (int j = 0; j < 4; j++) acc[j] += kks[k0 + 4 * j][n] * wv;
    }
#pragma unroll
    for (int j = 0; j < 4; j++)
        atomicAdd(&lam[((size_t)b * Kk + k0 + 4 * j) * Vv + v], acc[j]);
}

// ---------------- Kernel 5: fused position-lambda + apply (restructured) ----------------
// TN=64 positions/block, 256 threads = 8 v-groups x 32 n-pairs; 2 adjacent n per thread.
#define TN 64
__global__ __launch_bounds__(256, 2) void fused_out_kernel(
    const float* __restrict__ y, const float* __restrict__ lam,
    const float* __restrict__ conv_w, const float* __restrict__ conv_b,
    float* __restrict__ out) {
    __shared__ float  vvs[Vv][88];        // j in [0,86): vv[n0-11 .. n0+75); 22528 B
    __shared__ ushort qs[64][64];         // bf16 q channels; 8192 B
    __shared__ float  gs[Hh][Rr][TN];     // 23552 B
    __shared__ float  lcs[Kk][Vv];        // 4096 B
    __shared__ float  cws[Kk][24];        // padded row 24; 1536 B

    int b = blockIdx.y;
    int n0 = blockIdx.x * TN;
    int t = threadIdx.x;
    const float* yb = y + (size_t)b * Cc * Nn;

    // ---- stage ----
    for (int i = t; i < Kk * Rr; i += 256) cws[i / Rr][i % Rr] = conv_w[i];
    if (t < Kk) cws[t][23] = 0.f;
    for (int i = t; i < Kk * Vv; i += 256)
        lcs[i >> 6][i & 63] = lam[(size_t)b * Kk * Vv + i] + conv_b[i >> 6];
    for (int i = t; i < 64 * TN; i += 256) {
        int c = i >> 6, nl = i & 63;
        qs[c][nl] = f2bf(yb[(size_t)c * Nn + n0 + nl]);
    }
    for (int i = t; i < Vv * 86; i += 256) {
        int v = i / 86, j = i - v * 86;
        int n = n0 + j - 11;
        vvs[v][j] = (n >= 0 && n < Nn) ? yb[(size_t)(80 + v) * Nn + n] : 0.f;
    }
    __syncthreads();

    // ---- g phase: wave h computes g[h][r][nl] for its 64 nl ----
    {
        int h = t >> 6, nl = t & 63;
        float gacc[23];
#pragma unroll
        for (int r = 0; r < 23; r++) gacc[r] = 0.f;
#pragma unroll
        for (int k = 0; k < 16; k++) {
            float qv = bf2f(qs[h * 16 + k][nl]);
            const float4* cr = reinterpret_cast<const float4*>(&cws[k][0]);
#pragma unroll
            for (int q4 = 0; q4 < 6; q4++) {
                float4 c4 = cr[q4];
                int rb = q4 * 4;
                gacc[rb + 0] += qv * c4.x;
                if (rb + 1 < 23) gacc[rb + 1] += qv * c4.y;
                if (rb + 2 < 23) gacc[rb + 2] += qv * c4.z;
                if (rb + 3 < 23) gacc[rb + 3] += qv * c4.w;
            }
        }
#pragma unroll
        for (int r = 0; r < 23; r++) gs[h][r][nl] = gacc[r];
    }
    __syncthreads();

    // ---- main: thread owns (vbase..vbase+7) x (nl0, nl0+1) ----
    int np = t & 31;
    int vbase = (t >> 5) * 8;
    int nl0 = 2 * np;

    float acc[4][8][2];
#pragma unroll
    for (int h = 0; h < 4; h++)
#pragma unroll
        for (int vl = 0; vl < 8; vl++) {
            acc[h][vl][0] = 0.f;
            acc[h][vl][1] = 0.f;
        }

    // position part: sliding window over vv
    float wprev[8];
#pragma unroll
    for (int vl = 0; vl < 8; vl++) wprev[vl] = vvs[vbase + vl][nl0];
#pragma unroll
    for (int r = 0; r < 23; r++) {
        float g0[4], g1[4];
#pragma unroll
        for (int h = 0; h < 4; h++) {
            g0[h] = gs[h][r][nl0];
            g1[h] = gs[h][r][nl0 + 1];
        }
#pragma unroll
        for (int vl = 0; vl < 8; vl++) {
            float wc = vvs[vbase + vl][nl0 + 1 + r];
#pragma unroll
            for (int h = 0; h < 4; h++) {
                acc[h][vl][0] += g0[h] * wprev[vl];
                acc[h][vl][1] += g1[h] * wc;
            }
            wprev[vl] = wc;
        }
    }

    // content part: bf16 q pairs, lam_c+bias from LDS
#pragma unroll
    for (int k = 0; k < 16; k++) {
        float q0[4], q1[4];
#pragma unroll
        for (int h = 0; h < 4; h++) {
            uint u = *reinterpret_cast<const uint*>(&qs[h * 16 + k][nl0]);
            q0[h] = __uint_as_float(u << 16);
            q1[h] = __uint_as_float(u & 0xffff0000u);
        }
        const float4* lr = reinterpret_cast<const float4*>(&lcs[k][vbase]);
        float4 la = lr[0], lb = lr[1];
        float lc[8] = {la.x, la.y, la.z, la.w, lb.x, lb.y, lb.z, lb.w};
#pragma unroll
        for (int vl = 0; vl < 8; vl++) {
#pragma unroll
            for (int h = 0; h < 4; h++) {
                acc[h][vl][0] += q0[h] * lc[vl];
                acc[h][vl][1] += q1[h] * lc[vl];
            }
        }
    }

    // store float2 per (h, vl)
#pragma unroll
    for (int h = 0; h < 4; h++)
#pragma unroll
        for (int vl = 0; vl < 8; vl++) {
            float2 o;
            o.x = acc[h][vl][0];
            o.y = acc[h][vl][1];
            *reinterpret_cast<float2*>(
                &out[((size_t)b * 256 + h * 64 + vbase + vl) * Nn + n0 + nl0]) = o;
        }
}

extern "C" void kernel_launch(void* const* d_in, const int* in_sizes, int n_in,
                              void* d_out, int out_size, void* d_ws, size_t ws_size,
                              hipStream_t stream) {
    const float* x      = (const float*)d_in[0];
    const float* Wq     = (const float*)d_in[1];
    const float* qg     = (const float*)d_in[2];
    const float* qb     = (const float*)d_in[3];
    const float* qm     = (const float*)d_in[4];
    const float* qv     = (const float*)d_in[5];
    const float* Wk     = (const float*)d_in[6];
    const float* Wv     = (const float*)d_in[7];
    const float* vg     = (const float*)d_in[8];
    const float* vb     = (const float*)d_in[9];
    const float* vm     = (const float*)d_in[10];
    const float* vvar   = (const float*)d_in[11];
    const float* conv_w = (const float*)d_in[12];
    const float* conv_b = (const float*)d_in[13];
    float* out = (float*)d_out;

    float* wsf = (float*)d_ws;
    ushort* Wf16 = (ushort*)wsf;                 // 36864 ushort
    float* bias  = wsf + 18432;                  // 144 floats
    float* y     = wsf + 18432 + 256;            // 16*144*4096 floats
    float* lam   = y + (size_t)Bn * Cc * Nn;     // 16*16*64 floats

    pack_kernel<<<Cc, 256, 0, stream>>>(Wq, qg, qb, qm, qv, Wk, Wv, vg, vb, vm, vvar, Wf16, bias);
    proj_mfma_kernel<<<dim3(Nn / 64, Bn), 256, 0, stream>>>(x, Wf16, bias, y);
    softmax_kernel<<<dim3(Kk, Bn), 256, 0, stream>>>(y);
    hipMemsetAsync(lam, 0, (size_t)Bn * Kk * Vv * sizeof(float), stream);
    lamc_kernel<<<dim3(Nn / NCHUNK, Bn), 256, 0, stream>>>(y, lam);
    fused_out_kernel<<<dim3(Nn / TN, Bn), 256, 0, stream>>>(y, lam, conv_w, conv_b, out);
}

// Round 5
// 88.796 us; speedup vs baseline: 1.1264x; 1.1264x over previous
//
#include <hip/hip_runtime.h>
#include <hip/hip_bf16.h>

typedef unsigned int uint;
typedef unsigned short ushort;

// Dims
#define Bn 16
#define Dd 256
#define Nn 4096
#define Hh 4
#define Kk 16
#define Vv 64
#define Rr 23
#define Cc 144   // 64 q + 16 k + 64 v

typedef short bf16x8s __attribute__((ext_vector_type(8)));
typedef float f32x4 __attribute__((ext_vector_type(4)));

static __device__ __forceinline__ ushort f2bf(float f) {
    __hip_bfloat16 h = __float2bfloat16(f);
    return __builtin_bit_cast(ushort, h);
}
static __device__ __forceinline__ float bf2f(ushort u) {
    return __uint_as_float(((uint)u) << 16);
}
static __device__ __forceinline__ float bflo(uint u) { return __uint_as_float(u << 16); }
static __device__ __forceinline__ float bfhi(uint u) { return __uint_as_float(u & 0xffff0000u); }

// ---------------- Kernel 1: pack BN-folded weights (bf16, A-fragment order) ----------------
__global__ __launch_bounds__(256) void pack_kernel(
    const float* __restrict__ Wq, const float* __restrict__ qg, const float* __restrict__ qb,
    const float* __restrict__ qm, const float* __restrict__ qv,
    const float* __restrict__ Wk, const float* __restrict__ Wv,
    const float* __restrict__ vg, const float* __restrict__ vb,
    const float* __restrict__ vm, const float* __restrict__ vvar,
    ushort* __restrict__ Wf16, float* __restrict__ bias) {
    int c = blockIdx.x;       // 0..143
    int d = threadIdx.x;      // 0..255
    float scale, bs;
    const float* src;
    if (c < 64) {
        scale = qg[c] * rsqrtf(qv[c] + 1e-5f);
        bs = qb[c] - qm[c] * scale;
        src = Wq + c * Dd;
    } else if (c < 80) {
        scale = 1.f; bs = 0.f;
        src = Wk + (c - 64) * Dd;
    } else {
        int j = c - 80;
        scale = vg[j] * rsqrtf(vvar[j] + 1e-5f);
        bs = vb[j] - vm[j] * scale;
        src = Wv + j * Dd;
    }
    int rt = c >> 4, lm = c & 15;
    int kk = d >> 5, hi = (d >> 3) & 3, j = d & 7;
    int idx = ((rt * 8 + kk) * 64 + hi * 16 + lm) * 8 + j;
    Wf16[idx] = f2bf(src[d] * scale);
    if (d == 0) bias[c] = bs;
}

// ---------------- Kernel 2: MFMA projection y[b][144][4096] ----------------
__global__ __launch_bounds__(256, 4) void proj_mfma_kernel(
    const float* __restrict__ x, const ushort* __restrict__ Wf16,
    const float* __restrict__ bias, float* __restrict__ y) {
    __shared__ ushort Wlds[9 * 4 * 64 * 8];   // 36864 B

    int b = blockIdx.y;
    int n0 = blockIdx.x * 64;
    int t = threadIdx.x;
    int w = t >> 6;            // wave 0..3
    int l = t & 63;
    int lm = l & 15;
    int hi = l >> 4;           // 0..3
    int n = n0 + w * 16 + lm;  // this lane's output column

    const uint* WfU = (const uint*)Wf16;
    uint* WldsU = (uint*)Wlds;

    f32x4 acc[9];
#pragma unroll
    for (int rt = 0; rt < 9; rt++) acc[rt] = (f32x4){0.f, 0.f, 0.f, 0.f};

    const float* xb = x + (size_t)b * Dd * Nn + n;

#pragma unroll
    for (int p = 0; p < 2; p++) {
        int kb = p * 4;
        if (p) __syncthreads();
#pragma unroll
        for (int i = 0; i < 36; i++) {
            int flat = t + 256 * i;
            int f2 = flat >> 8;        // rt*4 + kkl
            int within = flat & 255;
            int rt = f2 >> 2, kkl = f2 & 3;
            WldsU[flat] = WfU[((rt * 8 + kb + kkl) << 8) + within];
        }
        __syncthreads();

#pragma unroll
        for (int kkl = 0; kkl < 4; kkl++) {
            int kk = kb + kkl;
            const float* xp = xb + (size_t)(kk * 32 + hi * 8) * Nn;
            float f[8];
#pragma unroll
            for (int j = 0; j < 8; j++) f[j] = xp[(size_t)j * Nn];
            bf16x8s bfrag;
#pragma unroll
            for (int j = 0; j < 8; j++) bfrag[j] = (short)f2bf(f[j]);
#pragma unroll
            for (int rt = 0; rt < 9; rt++) {
                bf16x8s afrag = *reinterpret_cast<const bf16x8s*>(
                    &Wlds[(size_t)((rt * 4 + kkl) * 64 + l) * 8]);
                acc[rt] = __builtin_amdgcn_mfma_f32_16x16x32_bf16(afrag, bfrag, acc[rt], 0, 0, 0);
            }
        }
    }

    float* yb = y + (size_t)b * Cc * Nn + n;
#pragma unroll
    for (int rt = 0; rt < 9; rt++) {
#pragma unroll
        for (int r = 0; r < 4; r++) {
            int c = rt * 16 + hi * 4 + r;
            yb[(size_t)c * Nn] = acc[rt][r] + bias[c];
        }
    }
}

// ---------------- Kernel 3: softmax over n for k channels ----------------
__global__ __launch_bounds__(256) void softmax_kernel(float* __restrict__ y) {
    int b = blockIdx.y, kc = blockIdx.x;
    float* row = y + ((size_t)b * Cc + 64 + kc) * Nn;
    int t = threadIdx.x;
    float vals[16];
    float m = -1e30f;
#pragma unroll
    for (int i = 0; i < 16; i++) {
        vals[i] = row[t + 256 * i];
        m = fmaxf(m, vals[i]);
    }
#pragma unroll
    for (int off = 32; off; off >>= 1) m = fmaxf(m, __shfl_xor(m, off));
    __shared__ float sm[4], ss[4];
    int wave = t >> 6;
    if ((t & 63) == 0) sm[wave] = m;
    __syncthreads();
    m = fmaxf(fmaxf(sm[0], sm[1]), fmaxf(sm[2], sm[3]));
    float s = 0.f;
#pragma unroll
    for (int i = 0; i < 16; i++) {
        vals[i] = __expf(vals[i] - m);
        s += vals[i];
    }
#pragma unroll
    for (int off = 32; off; off >>= 1) s += __shfl_xor(s, off);
    if ((t & 63) == 0) ss[wave] = s;
    __syncthreads();
    s = ss[0] + ss[1] + ss[2] + ss[3];
    float inv = 1.f / s;
#pragma unroll
    for (int i = 0; i < 16; i++) row[t + 256 * i] = vals[i] * inv;
}

// ---------------- Kernel 4: lam_c[b][16][64] = sum_n kk*vv ----------------
#define NCHUNK 128
__global__ __launch_bounds__(256) void lamc_kernel(
    const float* __restrict__ y, float* __restrict__ lam) {
    int b = blockIdx.y, ch = blockIdx.x;
    int n0 = ch * NCHUNK;
    __shared__ float kks[Kk][NCHUNK + 1];
    __shared__ float vvs[Vv][NCHUNK + 1];
    const float* yb = y + (size_t)b * Cc * Nn;
    int t = threadIdx.x;
#pragma unroll
    for (int i = 0; i < (Kk * NCHUNK) / 256; i++) {
        int idx = t + 256 * i;
        int r = idx >> 7, n = idx & 127;
        kks[r][n] = yb[(size_t)(64 + r) * Nn + n0 + n];
    }
#pragma unroll
    for (int i = 0; i < (Vv * NCHUNK) / 256; i++) {
        int idx = t + 256 * i;
        int r = idx >> 7, n = idx & 127;
        vvs[r][n] = yb[(size_t)(80 + r) * Nn + n0 + n];
    }
    __syncthreads();
    int v = t & 63;
    int k0 = t >> 6;   // 0..3
    float acc[4] = {0.f, 0.f, 0.f, 0.f};
    for (int n = 0; n < NCHUNK; n++) {
        float wv = vvs[v][n];
#pragma unroll
        for (int j = 0; j < 4; j++) acc[j] += kks[k0 + 4 * j][n] * wv;
    }
#pragma unroll
    for (int j = 0; j < 4; j++)
        atomicAdd(&lam[((size_t)b * Kk + k0 + 4 * j) * Vv + v], acc[j]);
}

// ---------------- Kernel 5: fused position-lambda + apply (wide-LDS version) ----------------
// TN=32 positions/block, 256 threads: thread = (vg 0..7 : 8 v) x (np 0..31 : 1 n).
// acc[4 h][8 v] per thread. All inner-loop LDS accesses are b64/b128 or broadcast.
#define TN 32
__global__ __launch_bounds__(256, 4) void fused_out_kernel(
    const float* __restrict__ y, const float* __restrict__ lam,
    const float* __restrict__ conv_w, const float* __restrict__ conv_b,
    float* __restrict__ out) {
    __shared__ ushort vvsT[54][72];       // [j][v] bf16, 144 B rows; j: window n0-11+j
    __shared__ ushort qsTh[TN][68];       // [np][k*4+h] bf16, 136 B rows
    __shared__ ushort gsT[Rr][TN][4];     // [r][np][h] bf16
    __shared__ float  lcs[Kk][Vv];        // lam_c + conv_b, fp32
    __shared__ float  cwsT[Rr][16];       // conv_w transposed [r][k], fp32

    int b = blockIdx.y;
    int n0 = blockIdx.x * TN;
    int t = threadIdx.x;
    const float* yb = y + (size_t)b * Cc * Nn;

    // ---- stage ----
    for (int i = t; i < Rr * 16; i += 256) {
        int r = i >> 4, k = i & 15;
        cwsT[r][k] = conv_w[k * Rr + r];
    }
    for (int i = t; i < Kk * Vv; i += 256)
        lcs[i >> 6][i & 63] = lam[(size_t)b * Kk * Vv + i] + conv_b[i >> 6];
    for (int i = t; i < 64 * TN; i += 256) {
        int c = i >> 5, nl = i & 31;
        qsTh[nl][(c & 15) * 4 + (c >> 4)] = f2bf(yb[(size_t)c * Nn + n0 + nl]);
    }
    for (int i = t; i < Vv * 54; i += 256) {
        int v = i / 54, j = i - v * 54;
        int n = n0 - 11 + j;
        float f = (n >= 0 && n < Nn) ? yb[(size_t)(80 + v) * Nn + n] : 0.f;
        vvsT[j][v] = f2bf(f);
    }
    __syncthreads();

    // ---- g phase: 128 threads, thread = (h, nl); q cached in regs ----
    if (t < 128) {
        int h = t >> 5, nl = t & 31;
        float qreg[16];
#pragma unroll
        for (int k = 0; k < 16; k++) qreg[k] = bf2f(qsTh[nl][k * 4 + h]);
#pragma unroll
        for (int r = 0; r < Rr; r++) {
            const float4* cr = reinterpret_cast<const float4*>(&cwsT[r][0]);
            float4 c0 = cr[0], c1 = cr[1], c2 = cr[2], c3 = cr[3];
            float g = qreg[0] * c0.x + qreg[1] * c0.y + qreg[2] * c0.z + qreg[3] * c0.w
                    + qreg[4] * c1.x + qreg[5] * c1.y + qreg[6] * c1.z + qreg[7] * c1.w
                    + qreg[8] * c2.x + qreg[9] * c2.y + qreg[10] * c2.z + qreg[11] * c2.w
                    + qreg[12] * c3.x + qreg[13] * c3.y + qreg[14] * c3.z + qreg[15] * c3.w;
            gsT[r][nl][h] = f2bf(g);
        }
    }
    __syncthreads();

    // ---- main ----
    int np = t & 31;
    int vg = t >> 5;

    float acc[4][8];
#pragma unroll
    for (int h = 0; h < 4; h++)
#pragma unroll
        for (int vl = 0; vl < 8; vl++) acc[h][vl] = 0.f;

    // position part: per r, 1 b64 (g, 4 h) + 1 b128 (vv, 8 v), 32 FMA
#pragma unroll
    for (int r = 0; r < Rr; r++) {
        ushort4 g4 = *reinterpret_cast<const ushort4*>(&gsT[r][np][0]);
        uint4 w4 = *reinterpret_cast<const uint4*>(&vvsT[np + r][vg * 8]);
        float gh[4] = {bf2f(g4.x), bf2f(g4.y), bf2f(g4.z), bf2f(g4.w)};
        float wv[8];
        wv[0] = bflo(w4.x); wv[1] = bfhi(w4.x);
        wv[2] = bflo(w4.y); wv[3] = bfhi(w4.y);
        wv[4] = bflo(w4.z); wv[5] = bfhi(w4.z);
        wv[6] = bflo(w4.w); wv[7] = bfhi(w4.w);
#pragma unroll
        for (int h = 0; h < 4; h++)
#pragma unroll
            for (int vl = 0; vl < 8; vl++) acc[h][vl] += gh[h] * wv[vl];
    }

    // content part: per k, 1 b64 (q, 4 h) + 2 broadcast b128 (lc), 32 FMA
#pragma unroll
    for (int k = 0; k < 16; k++) {
        ushort4 q4 = *reinterpret_cast<const ushort4*>(&qsTh[np][k * 4]);
        float qh[4] = {bf2f(q4.x), bf2f(q4.y), bf2f(q4.z), bf2f(q4.w)};
        const float4* lr = reinterpret_cast<const float4*>(&lcs[k][vg * 8]);
        float4 la = lr[0], lb = lr[1];
        float lv[8] = {la.x, la.y, la.z, la.w, lb.x, lb.y, lb.z, lb.w};
#pragma unroll
        for (int h = 0; h < 4; h++)
#pragma unroll
            for (int vl = 0; vl < 8; vl++) acc[h][vl] += qh[h] * lv[vl];
    }

    // store: coalesced 128 B segments per (h, vl)
    float* ob = out + (size_t)b * 256 * Nn + n0 + np;
#pragma unroll
    for (int h = 0; h < 4; h++)
#pragma unroll
        for (int vl = 0; vl < 8; vl++)
            ob[(size_t)(h * 64 + vg * 8 + vl) * Nn] = acc[h][vl];
}

extern "C" void kernel_launch(void* const* d_in, const int* in_sizes, int n_in,
                              void* d_out, int out_size, void* d_ws, size_t ws_size,
                              hipStream_t stream) {
    const float* x      = (const float*)d_in[0];
    const float* Wq     = (const float*)d_in[1];
    const float* qg     = (const float*)d_in[2];
    const float* qb     = (const float*)d_in[3];
    const float* qm     = (const float*)d_in[4];
    const float* qv     = (const float*)d_in[5];
    const float* Wk     = (const float*)d_in[6];
    const float* Wv     = (const float*)d_in[7];
    const float* vg     = (const float*)d_in[8];
    const float* vb     = (const float*)d_in[9];
    const float* vm     = (const float*)d_in[10];
    const float* vvar   = (const float*)d_in[11];
    const float* conv_w = (const float*)d_in[12];
    const float* conv_b = (const float*)d_in[13];
    float* out = (float*)d_out;

    float* wsf = (float*)d_ws;
    ushort* Wf16 = (ushort*)wsf;                 // 36864 ushort
    float* bias  = wsf + 18432;                  // 144 floats
    float* y     = wsf + 18432 + 256;            // 16*144*4096 floats
    float* lam   = y + (size_t)Bn * Cc * Nn;     // 16*16*64 floats

    pack_kernel<<<Cc, 256, 0, stream>>>(Wq, qg, qb, qm, qv, Wk, Wv, vg, vb, vm, vvar, Wf16, bias);
    proj_mfma_kernel<<<dim3(Nn / 64, Bn), 256, 0, stream>>>(x, Wf16, bias, y);
    softmax_kernel<<<dim3(Kk, Bn), 256, 0, stream>>>(y);
    hipMemsetAsync(lam, 0, (size_t)Bn * Kk * Vv * sizeof(float), stream);
    lamc_kernel<<<dim3(Nn / NCHUNK, Bn), 256, 0, stream>>>(y, lam);
    fused_out_kernel<<<dim3(Nn / TN, Bn), 256, 0, stream>>>(y, lam, conv_w, conv_b, out);
}

// Round 6
// 85.267 us; speedup vs baseline: 1.1730x; 1.0414x over previous
//
#include <hip/hip_runtime.h>
#include <hip/hip_bf16.h>

typedef unsigned int uint;
typedef unsigned short ushort;

// Dims
#define Bn 16
#define Dd 256
#define Nn 4096
#define Hh 4
#define Kk 16
#define Vv 64
#define Rr 23
#define Cc 144   // 64 q + 16 k + 64 v

typedef short bf16x8s __attribute__((ext_vector_type(8)));
typedef float f32x4 __attribute__((ext_vector_type(4)));

static __device__ __forceinline__ ushort f2bf(float f) {
    __hip_bfloat16 h = __float2bfloat16(f);
    return __builtin_bit_cast(ushort, h);
}
static __device__ __forceinline__ float bf2f(ushort u) {
    return __uint_as_float(((uint)u) << 16);
}
static __device__ __forceinline__ float bflo(uint u) { return __uint_as_float(u << 16); }
static __device__ __forceinline__ float bfhi(uint u) { return __uint_as_float(u & 0xffff0000u); }

// ---------------- Kernel 1: pack BN-folded weights (bf16, A-fragment order) ----------------
__global__ __launch_bounds__(256) void pack_kernel(
    const float* __restrict__ Wq, const float* __restrict__ qg, const float* __restrict__ qb,
    const float* __restrict__ qm, const float* __restrict__ qv,
    const float* __restrict__ Wk, const float* __restrict__ Wv,
    const float* __restrict__ vg, const float* __restrict__ vb,
    const float* __restrict__ vm, const float* __restrict__ vvar,
    ushort* __restrict__ Wf16, float* __restrict__ bias) {
    int c = blockIdx.x;       // 0..143
    int d = threadIdx.x;      // 0..255
    float scale, bs;
    const float* src;
    if (c < 64) {
        scale = qg[c] * rsqrtf(qv[c] + 1e-5f);
        bs = qb[c] - qm[c] * scale;
        src = Wq + c * Dd;
    } else if (c < 80) {
        scale = 1.f; bs = 0.f;
        src = Wk + (c - 64) * Dd;
    } else {
        int j = c - 80;
        scale = vg[j] * rsqrtf(vvar[j] + 1e-5f);
        bs = vb[j] - vm[j] * scale;
        src = Wv + j * Dd;
    }
    int rt = c >> 4, lm = c & 15;
    int kk = d >> 5, hi = (d >> 3) & 3, j = d & 7;
    int idx = ((rt * 8 + kk) * 64 + hi * 16 + lm) * 8 + j;
    Wf16[idx] = f2bf(src[d] * scale);
    if (d == 0) bias[c] = bs;
}

// ---------------- Kernel 2: MFMA projection y[b][144][4096] ----------------
__global__ __launch_bounds__(256, 4) void proj_mfma_kernel(
    const float* __restrict__ x, const ushort* __restrict__ Wf16,
    const float* __restrict__ bias, float* __restrict__ y) {
    __shared__ ushort Wlds[9 * 4 * 64 * 8];   // 36864 B

    int b = blockIdx.y;
    int n0 = blockIdx.x * 64;
    int t = threadIdx.x;
    int w = t >> 6;            // wave 0..3
    int l = t & 63;
    int lm = l & 15;
    int hi = l >> 4;           // 0..3
    int n = n0 + w * 16 + lm;  // this lane's output column

    const uint* WfU = (const uint*)Wf16;
    uint* WldsU = (uint*)Wlds;

    f32x4 acc[9];
#pragma unroll
    for (int rt = 0; rt < 9; rt++) acc[rt] = (f32x4){0.f, 0.f, 0.f, 0.f};

    const float* xb = x + (size_t)b * Dd * Nn + n;

#pragma unroll
    for (int p = 0; p < 2; p++) {
        int kb = p * 4;
        if (p) __syncthreads();
#pragma unroll
        for (int i = 0; i < 36; i++) {
            int flat = t + 256 * i;
            int f2 = flat >> 8;        // rt*4 + kkl
            int within = flat & 255;
            int rt = f2 >> 2, kkl = f2 & 3;
            WldsU[flat] = WfU[((rt * 8 + kb + kkl) << 8) + within];
        }
        __syncthreads();

#pragma unroll
        for (int kkl = 0; kkl < 4; kkl++) {
            int kk = kb + kkl;
            const float* xp = xb + (size_t)(kk * 32 + hi * 8) * Nn;
            float f[8];
#pragma unroll
            for (int j = 0; j < 8; j++) f[j] = xp[(size_t)j * Nn];
            bf16x8s bfrag;
#pragma unroll
            for (int j = 0; j < 8; j++) bfrag[j] = (short)f2bf(f[j]);
#pragma unroll
            for (int rt = 0; rt < 9; rt++) {
                bf16x8s afrag = *reinterpret_cast<const bf16x8s*>(
                    &Wlds[(size_t)((rt * 4 + kkl) * 64 + l) * 8]);
                acc[rt] = __builtin_amdgcn_mfma_f32_16x16x32_bf16(afrag, bfrag, acc[rt], 0, 0, 0);
            }
        }
    }

    float* yb = y + (size_t)b * Cc * Nn + n;
#pragma unroll
    for (int rt = 0; rt < 9; rt++) {
#pragma unroll
        for (int r = 0; r < 4; r++) {
            int c = rt * 16 + hi * 4 + r;
            yb[(size_t)c * Nn] = acc[rt][r] + bias[c];
        }
    }
}

// ---------------- Kernel 3: softmax over n for k channels ----------------
__global__ __launch_bounds__(256) void softmax_kernel(float* __restrict__ y) {
    int b = blockIdx.y, kc = blockIdx.x;
    float* row = y + ((size_t)b * Cc + 64 + kc) * Nn;
    int t = threadIdx.x;
    float vals[16];
    float m = -1e30f;
#pragma unroll
    for (int i = 0; i < 16; i++) {
        vals[i] = row[t + 256 * i];
        m = fmaxf(m, vals[i]);
    }
#pragma unroll
    for (int off = 32; off; off >>= 1) m = fmaxf(m, __shfl_xor(m, off));
    __shared__ float sm[4], ss[4];
    int wave = t >> 6;
    if ((t & 63) == 0) sm[wave] = m;
    __syncthreads();
    m = fmaxf(fmaxf(sm[0], sm[1]), fmaxf(sm[2], sm[3]));
    float s = 0.f;
#pragma unroll
    for (int i = 0; i < 16; i++) {
        vals[i] = __expf(vals[i] - m);
        s += vals[i];
    }
#pragma unroll
    for (int off = 32; off; off >>= 1) s += __shfl_xor(s, off);
    if ((t & 63) == 0) ss[wave] = s;
    __syncthreads();
    s = ss[0] + ss[1] + ss[2] + ss[3];
    float inv = 1.f / s;
#pragma unroll
    for (int i = 0; i < 16; i++) row[t + 256 * i] = vals[i] * inv;
}

// ---------------- Kernel 4: lam_c[b][16][64] = sum_n kk*vv ----------------
#define NCHUNK 128
__global__ __launch_bounds__(256) void lamc_kernel(
    const float* __restrict__ y, float* __restrict__ lam) {
    int b = blockIdx.y, ch = blockIdx.x;
    int n0 = ch * NCHUNK;
    __shared__ float kks[Kk][NCHUNK + 1];
    __shared__ float vvs[Vv][NCHUNK + 1];
    const float* yb = y + (size_t)b * Cc * Nn;
    int t = threadIdx.x;
#pragma unroll
    for (int i = 0; i < (Kk * NCHUNK) / 256; i++) {
        int idx = t + 256 * i;
        int r = idx >> 7, n = idx & 127;
        kks[r][n] = yb[(size_t)(64 + r) * Nn + n0 + n];
    }
#pragma unroll
    for (int i = 0; i < (Vv * NCHUNK) / 256; i++) {
        int idx = t + 256 * i;
        int r = idx >> 7, n = idx & 127;
        vvs[r][n] = yb[(size_t)(80 + r) * Nn + n0 + n];
    }
    __syncthreads();
    int v = t & 63;
    int k0 = t >> 6;   // 0..3
    float acc[4] = {0.f, 0.f, 0.f, 0.f};
    for (int n = 0; n < NCHUNK; n++) {
        float wv = vvs[v][n];
#pragma unroll
        for (int j = 0; j < 4; j++) acc[j] += kks[k0 + 4 * j][n] * wv;
    }
#pragma unroll
    for (int j = 0; j < 4; j++)
        atomicAdd(&lam[((size_t)b * Kk + k0 + 4 * j) * Vv + v], acc[j]);
}

// ---------------- Kernel 5: fused position-lambda + apply ----------------
// TN=32 positions/block, 256 threads = (vg 0..7) x (np 0..31). acc[4 h][8 v].
// Staging: constant-trip unrolled float4 loads (one latency exposure).
// LDS reads at bank-floor: qsTh fp32 b128, vvsT bf16 b128 (144 B rows), gsT bf16 b64.
#define TN 32
__global__ __launch_bounds__(256, 4) void fused_out_kernel(
    const float* __restrict__ y, const float* __restrict__ lam,
    const float* __restrict__ conv_w, const float* __restrict__ conv_b,
    float* __restrict__ out) {
    __shared__ ushort vvsT[64][72];       // [j][v] bf16; j <-> n = n0-12+j ; 144 B rows
    __shared__ float  qsTh[TN][68];       // [np][k*4+h] fp32; 272 B rows
    __shared__ ushort gsT[Rr][TN][4];     // [r][np][h] bf16
    __shared__ float  lcs[Kk][Vv];        // lam_c + conv_b
    __shared__ float  cwsT[Rr][16];       // conv_w transposed [r][k]

    int b = blockIdx.y;
    int n0 = blockIdx.x * TN;
    int t = threadIdx.x;
    const float* yb = y + (size_t)b * Cc * Nn;

    // ---- small tables ----
    for (int i = t; i < Rr * 16; i += 256) {
        int r = i >> 4, k = i & 15;
        cwsT[r][k] = conv_w[k * Rr + r];
    }
    for (int i = t; i < Kk * Vv; i += 256)
        lcs[i >> 6][i & 63] = lam[(size_t)b * Kk * Vv + i] + conv_b[i >> 6];

    // ---- q staging: 2 float4 loads/thread, unrolled ----
#pragma unroll
    for (int m = 0; m < 2; m++) {
        int idx = t + 256 * m;           // 0..511
        int c = idx >> 3, f4 = idx & 7;  // c: channel 0..63, f4: float4 within row
        float4 f = *reinterpret_cast<const float4*>(&yb[(size_t)c * Nn + n0 + f4 * 4]);
        int cp = (c & 15) * 4 + (c >> 4);
        qsTh[f4 * 4 + 0][cp] = f.x;
        qsTh[f4 * 4 + 1][cp] = f.y;
        qsTh[f4 * 4 + 2][cp] = f.z;
        qsTh[f4 * 4 + 3][cp] = f.w;
    }
    // ---- vv staging: 4 float4 loads/thread, window n0-12 .. n0+51 (4-aligned) ----
#pragma unroll
    for (int m = 0; m < 4; m++) {
        int idx = t + 256 * m;            // 0..1023
        int v = idx >> 4, f4 = idx & 15;
        int n = n0 - 12 + f4 * 4;
        const float* vp = &yb[(size_t)(80 + v) * Nn + n];
        float4 f;
        if (n >= 0 && n <= Nn - 4) {
            f = *reinterpret_cast<const float4*>(vp);
        } else {
            f.x = (n + 0 >= 0 && n + 0 < Nn) ? vp[0] : 0.f;
            f.y = (n + 1 >= 0 && n + 1 < Nn) ? vp[1] : 0.f;
            f.z = (n + 2 >= 0 && n + 2 < Nn) ? vp[2] : 0.f;
            f.w = (n + 3 >= 0 && n + 3 < Nn) ? vp[3] : 0.f;
        }
        vvsT[f4 * 4 + 0][v] = f2bf(f.x);
        vvsT[f4 * 4 + 1][v] = f2bf(f.y);
        vvsT[f4 * 4 + 2][v] = f2bf(f.z);
        vvsT[f4 * 4 + 3][v] = f2bf(f.w);
    }
    __syncthreads();

    // ---- g phase: all 256 threads; thread = (rh, h, nl); r split 0..11 / 12..22 ----
    {
        int rh = t >> 7;          // wave-pair uniform
        int h = (t >> 5) & 3;
        int nl = t & 31;
        float qreg[16];
#pragma unroll
        for (int k = 0; k < 16; k++) qreg[k] = qsTh[nl][k * 4 + h];
#pragma unroll
        for (int i = 0; i < 12; i++) {
            int r = rh * 12 + i;
            if (r < 23) {
                const float4* cr = reinterpret_cast<const float4*>(&cwsT[r][0]);
                float4 c0 = cr[0], c1 = cr[1], c2 = cr[2], c3 = cr[3];
                float g = qreg[0] * c0.x + qreg[1] * c0.y + qreg[2] * c0.z + qreg[3] * c0.w
                        + qreg[4] * c1.x + qreg[5] * c1.y + qreg[6] * c1.z + qreg[7] * c1.w
                        + qreg[8] * c2.x + qreg[9] * c2.y + qreg[10] * c2.z + qreg[11] * c2.w
                        + qreg[12] * c3.x + qreg[13] * c3.y + qreg[14] * c3.z + qreg[15] * c3.w;
                gsT[r][nl][h] = f2bf(g);
            }
        }
    }
    __syncthreads();

    // ---- main ----
    int np = t & 31;
    int vg = t >> 5;

    float acc[4][8];
#pragma unroll
    for (int h = 0; h < 4; h++)
#pragma unroll
        for (int vl = 0; vl < 8; vl++) acc[h][vl] = 0.f;

    // position part: per r, 1 b64 (g: 4 h) + 1 b128 (vv: 8 v bf16), 32 FMA
#pragma unroll
    for (int r = 0; r < Rr; r++) {
        ushort4 g4 = *reinterpret_cast<const ushort4*>(&gsT[r][np][0]);
        uint4 w4 = *reinterpret_cast<const uint4*>(&vvsT[np + r + 1][vg * 8]);
        float gh[4] = {bf2f(g4.x), bf2f(g4.y), bf2f(g4.z), bf2f(g4.w)};
        float wv[8];
        wv[0] = bflo(w4.x); wv[1] = bfhi(w4.x);
        wv[2] = bflo(w4.y); wv[3] = bfhi(w4.y);
        wv[4] = bflo(w4.z); wv[5] = bfhi(w4.z);
        wv[6] = bflo(w4.w); wv[7] = bfhi(w4.w);
#pragma unroll
        for (int h = 0; h < 4; h++)
#pragma unroll
            for (int vl = 0; vl < 8; vl++) acc[h][vl] += gh[h] * wv[vl];
    }

    // content part: per k, 1 b128 (q: 4 h fp32) + 2 broadcast b128 (lc), 32 FMA
#pragma unroll
    for (int k = 0; k < 16; k++) {
        float4 q4 = *reinterpret_cast<const float4*>(&qsTh[np][k * 4]);
        float qh[4] = {q4.x, q4.y, q4.z, q4.w};
        const float4* lr = reinterpret_cast<const float4*>(&lcs[k][vg * 8]);
        float4 la = lr[0], lb = lr[1];
        float lv[8] = {la.x, la.y, la.z, la.w, lb.x, lb.y, lb.z, lb.w};
#pragma unroll
        for (int h = 0; h < 4; h++)
#pragma unroll
            for (int vl = 0; vl < 8; vl++) acc[h][vl] += qh[h] * lv[vl];
    }

    // store: 32 coalesced b32 stores (128 B per (h,vl) across np)
    float* ob = out + (size_t)b * 256 * Nn + n0 + np;
#pragma unroll
    for (int h = 0; h < 4; h++)
#pragma unroll
        for (int vl = 0; vl < 8; vl++)
            ob[(size_t)(h * 64 + vg * 8 + vl) * Nn] = acc[h][vl];
}

extern "C" void kernel_launch(void* const* d_in, const int* in_sizes, int n_in,
                              void* d_out, int out_size, void* d_ws, size_t ws_size,
                              hipStream_t stream) {
    const float* x      = (const float*)d_in[0];
    const float* Wq     = (const float*)d_in[1];
    const float* qg     = (const float*)d_in[2];
    const float* qb     = (const float*)d_in[3];
    const float* qm     = (const float*)d_in[4];
    const float* qv     = (const float*)d_in[5];
    const float* Wk     = (const float*)d_in[6];
    const float* Wv     = (const float*)d_in[7];
    const float* vg     = (const float*)d_in[8];
    const float* vb     = (const float*)d_in[9];
    const float* vm     = (const float*)d_in[10];
    const float* vvar   = (const float*)d_in[11];
    const float* conv_w = (const float*)d_in[12];
    const float* conv_b = (const float*)d_in[13];
    float* out = (float*)d_out;

    float* wsf = (float*)d_ws;
    ushort* Wf16 = (ushort*)wsf;                 // 36864 ushort
    float* bias  = wsf + 18432;                  // 144 floats
    float* y     = wsf + 18432 + 256;            // 16*144*4096 floats
    float* lam   = y + (size_t)Bn * Cc * Nn;     // 16*16*64 floats

    pack_kernel<<<Cc, 256, 0, stream>>>(Wq, qg, qb, qm, qv, Wk, Wv, vg, vb, vm, vvar, Wf16, bias);
    proj_mfma_kernel<<<dim3(Nn / 64, Bn), 256, 0, stream>>>(x, Wf16, bias, y);
    softmax_kernel<<<dim3(Kk, Bn), 256, 0, stream>>>(y);
    hipMemsetAsync(lam, 0, (size_t)Bn * Kk * Vv * sizeof(float), stream);
    lamc_kernel<<<dim3(Nn / NCHUNK, Bn), 256, 0, stream>>>(y, lam);
    fused_out_kernel<<<dim3(Nn / TN, Bn), 256, 0, stream>>>(y, lam, conv_w, conv_b, out);
}